// Round 1
// baseline (232.223 us; speedup 1.0000x reference)
//
#include <hip/hip_runtime.h>

// TELIF: temporal-encoding LIF neuron scan.
// tx: [T, B, N] fp32, TE: [N, T] fp32, out ty: [T, B, N] fp32 (0/1 spikes).
// T=512, B=64, N=1024. One thread per (b,n) sequence; sequential over t.
// 65536 threads = 4 waves/CU (occupancy-capped by problem size) -> latency
// hiding via deep register double-buffered prefetch (16 tx loads in flight).

#define T_STEPS 512
#define BATCH   64
#define NNEUR   1024
#define BN      (BATCH * NNEUR)
#define UCHUNK  16

__global__ __launch_bounds__(256) void telif_kernel(
    const float* __restrict__ tx, const float* __restrict__ TE,
    float* __restrict__ out)
{
    // Reference is validated bit-for-bit-ish against numpy fp32 with a hard
    // (v > th) threshold: forbid FMA contraction so every mul/add rounds
    // exactly like the reference's elementwise ops.
#pragma clang fp contract(off)

    const int flat = blockIdx.x * 256 + threadIdx.x;   // b*N + n
    const int n = flat & (NNEUR - 1);

    const float* txp = tx + flat;        // stride BN along t, coalesced across lanes
    const float* tep = TE + n * T_STEPS; // contiguous along t per thread
    float*       outp = out + flat;

    float v  = 0.0f;   // REST
    float y  = 0.0f;
    float th = 0.3f;   // THRESHOLD

    float xc[UCHUNK], tc[UCHUNK];  // current chunk
    float xn[UCHUNK], tn[UCHUNK];  // next chunk (prefetch)

    // Prefetch chunk 0.
#pragma unroll
    for (int u = 0; u < UCHUNK; ++u)
        xc[u] = __builtin_nontemporal_load(txp + (size_t)u * BN);
#pragma unroll
    for (int u = 0; u < UCHUNK; u += 4) {
        float4 f = *reinterpret_cast<const float4*>(tep + u);
        tc[u] = f.x; tc[u + 1] = f.y; tc[u + 2] = f.z; tc[u + 3] = f.w;
    }

#pragma unroll 1
    for (int t = 0; t < T_STEPS; t += UCHUNK) {
        const int tb = t + UCHUNK;
        if (tb < T_STEPS) {
            // Issue next chunk's loads before computing current chunk:
            // keeps ~16 scalar loads + 4 float4 TE loads in flight per wave.
#pragma unroll
            for (int u = 0; u < UCHUNK; ++u)
                xn[u] = __builtin_nontemporal_load(txp + (size_t)(tb + u) * BN);
#pragma unroll
            for (int u = 0; u < UCHUNK; u += 4) {
                float4 f = *reinterpret_cast<const float4*>(tep + tb + u);
                tn[u] = f.x; tn[u + 1] = f.y; tn[u + 2] = f.z; tn[u + 3] = f.w;
            }
        }

        // Compute current chunk. Exact op order of the reference:
        //   th = th + v*te - (th - THRESHOLD)*BETA
        //   v  = v*DECAY*(1-y) + x
        //   y  = (v > th)
#pragma unroll
        for (int u = 0; u < UCHUNK; ++u) {
            float a    = v * tc[u];
            float bsum = th + a;
            float c    = th - 0.3f;
            float d    = c * 0.02f;
            th = bsum - d;
            float e  = v * 0.2f;
            float f1 = 1.0f - y;
            float g  = e * f1;
            v = g + xc[u];
            y = (v > th) ? 1.0f : 0.0f;
            __builtin_nontemporal_store(y, outp + (size_t)(t + u) * BN);
        }

        // Rotate buffers (register moves; garbage on last iter is unused).
#pragma unroll
        for (int u = 0; u < UCHUNK; ++u) { xc[u] = xn[u]; tc[u] = tn[u]; }
    }
}

extern "C" void kernel_launch(void* const* d_in, const int* in_sizes, int n_in,
                              void* d_out, int out_size, void* d_ws, size_t ws_size,
                              hipStream_t stream) {
    const float* tx = (const float*)d_in[0];  // [T, B, N]
    const float* TE = (const float*)d_in[1];  // [N, T]
    float* out = (float*)d_out;               // [T, B, N]
    telif_kernel<<<BN / 256, 256, 0, stream>>>(tx, TE, out);
}